// Round 1
// baseline (1263.150 us; speedup 1.0000x reference)
//
#include <hip/hip_runtime.h>
#include <hip/hip_bf16.h>

#define B_    16
#define S_    16
#define D_    4096
#define H_    32
#define KVH_  8
#define HD_   128
#define MAXS_ 4096
#define M_    256

using frag_ab = __attribute__((ext_vector_type(8))) short;   // 8 x bf16
using frag_cd = __attribute__((ext_vector_type(4))) float;   // 4 x f32

__device__ __forceinline__ short bfb(float f) {
  union { float f; unsigned u; } cv; cv.f = f;
  unsigned u = cv.u;
  return (short)((u + 0x7fffu + ((u >> 16) & 1u)) >> 16);  // RN-even fp32->bf16
}

// ---------------- W (K x N, f32) -> Wt (N x K, bf16) ----------------
__global__ __launch_bounds__(256) void transpose_convert(
    const float* __restrict__ W, short* __restrict__ Wt, int K, int N)
{
  __shared__ float tile[32][33];
  int n0 = blockIdx.x * 32;
  int k0 = blockIdx.y * 32;
  int tx = threadIdx.x;   // 0..31
  int ty = threadIdx.y;   // 0..7
#pragma unroll
  for (int i = 0; i < 4; i++) {
    int k = ty + i * 8;
    tile[k][tx] = W[(size_t)(k0 + k) * N + n0 + tx];
  }
  __syncthreads();
#pragma unroll
  for (int i = 0; i < 4; i++) {
    int n = ty + i * 8;
    Wt[(size_t)(n0 + n) * K + k0 + tx] = bfb(tile[tx][n]);
  }
}

// ---------------- GEMM: A (f32, MxK row-major) x Bt (bf16, NxK row-major) ----------------
// MODE 0: bf16 out; MODE 1: bf16 out + RoPE; MODE 2: f32 out
#define LDT 72   // padded LDS stride (bf16 elems) for 64-wide K tile

template<int MODE>
__global__ __launch_bounds__(256) void gemm_bt(
    const float* __restrict__ A, const short* __restrict__ Bt,
    void* __restrict__ Cout, int Ndim, int Kdim, const int* __restrict__ sp)
{
  __shared__ __align__(16) short lds_a[64 * LDT];
  __shared__ __align__(16) short lds_b[64 * LDT];
  int tid  = threadIdx.x;
  int wave = tid >> 6, lane = tid & 63, quad = lane >> 4, l16 = lane & 15;
  int m0 = blockIdx.y * 64;
  int n0 = blockIdx.x * 64;

  const frag_cd fz = {0.f, 0.f, 0.f, 0.f};
  frag_cd acc[4];
#pragma unroll
  for (int i = 0; i < 4; i++) acc[i] = fz;

  for (int kk = 0; kk < Kdim; kk += 64) {
    __syncthreads();
    // stage A: 64x64 f32 -> bf16 (coalesced: 16 lanes cover one 256B row)
#pragma unroll
    for (int i = 0; i < 4; i++) {
      int seg = i * 256 + tid;
      int m   = seg >> 4;
      int k4  = (seg & 15) << 2;
      float4 v = *(const float4*)(A + (size_t)(m0 + m) * Kdim + kk + k4);
      short4 pk;
      pk.x = bfb(v.x); pk.y = bfb(v.y); pk.z = bfb(v.z); pk.w = bfb(v.w);
      *(short4*)(&lds_a[m * LDT + k4]) = pk;
    }
    // stage B: 64x64 bf16 (16B per lane)
#pragma unroll
    for (int i = 0; i < 2; i++) {
      int seg = i * 256 + tid;
      int n   = seg >> 3;
      int k8  = (seg & 7) << 3;
      frag_ab v = *(const frag_ab*)(Bt + (size_t)(n0 + n) * Kdim + kk + k8);
      *(frag_ab*)(&lds_b[n * LDT + k8]) = v;
    }
    __syncthreads();
#pragma unroll
    for (int k0 = 0; k0 < 64; k0 += 32) {
      frag_ab af = *(const frag_ab*)(&lds_a[(wave * 16 + l16) * LDT + k0 + quad * 8]);
#pragma unroll
      for (int nt = 0; nt < 4; nt++) {
        frag_ab bf = *(const frag_ab*)(&lds_b[(nt * 16 + l16) * LDT + k0 + quad * 8]);
        acc[nt] = __builtin_amdgcn_mfma_f32_16x16x32_bf16(af, bf, acc[nt], 0, 0, 0);
      }
    }
  }

  int start_pos = (MODE == 1) ? *sp : 0;
#pragma unroll
  for (int nt = 0; nt < 4; nt++) {
    int n = n0 + nt * 16 + l16;
#pragma unroll
    for (int r = 0; r < 4; r++) {
      int m = m0 + wave * 16 + quad * 4 + r;
      float v = acc[nt][r];
      float outv = v;
      if (MODE == 1) {
        float partner = __shfl_xor(v, 1);  // lanes differ only in col bit0 -> paired (2i,2i+1)
        int hd = n & (HD_ - 1);
        int pi = hd >> 1;
        float theta = exp2f(-(float)pi * 0.2076205059304601f);  // log2(10000)/64
        float fr = (float)(start_pos + (m & 15)) * theta;
        float sn, cs;
        sincosf(fr, &sn, &cs);
        // even col: x_r*cos - x_i*sin ; odd col: x_r*sin + x_i*cos
        outv = v * cs + ((n & 1) ? partner * sn : -partner * sn);
      }
      if (MODE == 2) ((float*)Cout)[(size_t)m * Ndim + n] = outv;
      else           ((short*)Cout)[(size_t)m * Ndim + n] = bfb(outv);
    }
  }
}

// ---------------- flash attention, split-kv ----------------
#define TC  64
#define KLD 136   // k_s stride (128 hd + pad)
#define VLD 72    // vT stride (64 t + pad)
#define PLD 72

__global__ __launch_bounds__(256) void attn_kernel(
    const short* __restrict__ qb,        // 256 x 4096 bf16 (rope'd)
    const short* __restrict__ kb,        // 256 x 1024 bf16 (rope'd new keys)
    const short* __restrict__ vb,        // 256 x 1024 bf16
    const float* __restrict__ cache_k,   // 16 x 4096 x 8 x 128 f32
    const float* __restrict__ cache_v,
    float* __restrict__ part_ctx,        // [512][64][128]
    float* __restrict__ part_m,          // [512][64]
    float* __restrict__ part_l,
    const int* __restrict__ sp)
{
  __shared__ __align__(16) short k_s[TC * KLD];
  __shared__ __align__(16) short vT[HD_ * VLD];
  __shared__ __align__(16) short p_s[64 * PLD];

  int chunk = blockIdx.x, kvh = blockIdx.y, b = blockIdx.z;
  int tid = threadIdx.x;
  int wave = tid >> 6, lane = tid & 63, quad = lane >> 4, l16 = lane & 15;
  int start_pos = *sp;

  // q fragments for this wave's rep: rows s = l16, head = kvh*4 + wave
  frag_ab qf[4];
  {
    const short* qrow = qb + (size_t)(b * 16 + l16) * D_ + (kvh * 4 + wave) * HD_;
#pragma unroll
    for (int k0 = 0; k0 < 4; k0++)
      qf[k0] = *(const frag_ab*)(qrow + k0 * 32 + quad * 8);
  }

  const frag_cd fz = {0.f, 0.f, 0.f, 0.f};
  frag_cd acc_o[8];
#pragma unroll
  for (int i = 0; i < 8; i++) acc_o[i] = fz;
  float m_i[4], l_i[4];
#pragma unroll
  for (int r = 0; r < 4; r++) { m_i[r] = -1e30f; l_i[r] = 0.f; }

  int rloc = tid >> 5;
  int lane32 = tid & 31;
  int hd4 = lane32 * 4;
  const float scale = 0.08838834764831845f;  // 1/sqrt(128)

  for (int it = 0; it < 1024 / TC; it++) {
    int t0 = chunk * 1024 + it * TC;
    __syncthreads();
    // stage K [t][hd] and V^T [hd][t]; last 16 positions come from new k/v
#pragma unroll
    for (int pass = 0; pass < 8; pass++) {
      int row = pass * 8 + rloc;
      int t = t0 + row;
      short4 kq, vq;
      if (t < start_pos) {
        size_t off = (((size_t)b * MAXS_ + t) * KVH_ + kvh) * HD_ + hd4;
        float4 k4 = *(const float4*)(cache_k + off);
        float4 v4 = *(const float4*)(cache_v + off);
        kq.x = bfb(k4.x); kq.y = bfb(k4.y); kq.z = bfb(k4.z); kq.w = bfb(k4.w);
        vq.x = bfb(v4.x); vq.y = bfb(v4.y); vq.z = bfb(v4.z); vq.w = bfb(v4.w);
      } else {
        int s = t - start_pos;
        size_t off = (size_t)(b * 16 + s) * (KVH_ * HD_) + kvh * HD_ + hd4;
        kq = *(const short4*)(kb + off);
        vq = *(const short4*)(vb + off);
      }
      *(short4*)(&k_s[row * KLD + hd4]) = kq;
      vT[(hd4 + 0) * VLD + row] = vq.x;
      vT[(hd4 + 1) * VLD + row] = vq.y;
      vT[(hd4 + 2) * VLD + row] = vq.z;
      vT[(hd4 + 3) * VLD + row] = vq.w;
    }
    __syncthreads();

    // scores = Q K^T  (16 q-rows x 64 t per wave)
    frag_cd sc[4];
#pragma unroll
    for (int i = 0; i < 4; i++) sc[i] = fz;
#pragma unroll
    for (int k0 = 0; k0 < HD_; k0 += 32) {
#pragma unroll
      for (int nt = 0; nt < 4; nt++) {
        frag_ab bfm = *(const frag_ab*)(&k_s[(nt * 16 + l16) * KLD + k0 + quad * 8]);
        sc[nt] = __builtin_amdgcn_mfma_f32_16x16x32_bf16(qf[k0 >> 5], bfm, sc[nt], 0, 0, 0);
      }
    }

    // online softmax: row = quad*4+reg, its 16 cols live in the 16 lanes of this quad
    float alpha[4];
#pragma unroll
    for (int r = 0; r < 4; r++) {
      float mx = fmaxf(fmaxf(sc[0][r], sc[1][r]), fmaxf(sc[2][r], sc[3][r])) * scale;
#pragma unroll
      for (int off = 1; off < 16; off <<= 1) mx = fmaxf(mx, __shfl_xor(mx, off));
      float mnew = fmaxf(m_i[r], mx);
      alpha[r] = __expf(m_i[r] - mnew);
      m_i[r] = mnew;
      float rsum = 0.f;
#pragma unroll
      for (int nt = 0; nt < 4; nt++) {
        float p = __expf(sc[nt][r] * scale - mnew);
        sc[nt][r] = p;
        rsum += p;
      }
#pragma unroll
      for (int off = 1; off < 16; off <<= 1) rsum += __shfl_xor(rsum, off);
      l_i[r] = l_i[r] * alpha[r] + rsum;
    }
#pragma unroll
    for (int nt = 0; nt < 8; nt++)
#pragma unroll
      for (int r = 0; r < 4; r++) acc_o[nt][r] *= alpha[r];

    // P: C-layout -> LDS -> A-layout (wave-private rows, no barrier needed)
#pragma unroll
    for (int r = 0; r < 4; r++)
#pragma unroll
      for (int nt = 0; nt < 4; nt++)
        p_s[(wave * 16 + quad * 4 + r) * PLD + nt * 16 + l16] = bfb(sc[nt][r]);

    // ctx += P V
#pragma unroll
    for (int k0 = 0; k0 < TC; k0 += 32) {
      frag_ab af = *(const frag_ab*)(&p_s[(wave * 16 + l16) * PLD + k0 + quad * 8]);
#pragma unroll
      for (int nt = 0; nt < 8; nt++) {
        frag_ab bfm = *(const frag_ab*)(&vT[(nt * 16 + l16) * VLD + k0 + quad * 8]);
        acc_o[nt] = __builtin_amdgcn_mfma_f32_16x16x32_bf16(af, bfm, acc_o[nt], 0, 0, 0);
      }
    }
  }

  int blk = (b * 8 + kvh) * 4 + chunk;
#pragma unroll
  for (int nt = 0; nt < 8; nt++)
#pragma unroll
    for (int r = 0; r < 4; r++) {
      int qrow = wave * 16 + quad * 4 + r;
      part_ctx[((size_t)blk * 64 + qrow) * HD_ + nt * 16 + l16] = acc_o[nt][r];
    }
  if (l16 == 0) {
#pragma unroll
    for (int r = 0; r < 4; r++) {
      int qrow = wave * 16 + quad * 4 + r;
      part_m[blk * 64 + qrow] = m_i[r];
      part_l[blk * 64 + qrow] = l_i[r];
    }
  }
}

// ---------------- combine split-kv partials -> ctx (256 x 4096 f32) ----------------
__global__ __launch_bounds__(256) void combine_kernel(
    const float* __restrict__ part_ctx, const float* __restrict__ part_m,
    const float* __restrict__ part_l, float* __restrict__ ctx)
{
  int bk = blockIdx.x;            // b*8 + kvh
  int b = bk >> 3, kvh = bk & 7;
  for (int idx = threadIdx.x; idx < 64 * 128; idx += 256) {
    int qrow = idx >> 7;
    int hd = idx & 127;
    float M = -1e30f;
#pragma unroll
    for (int c = 0; c < 4; c++) M = fmaxf(M, part_m[(bk * 4 + c) * 64 + qrow]);
    float lsum = 0.f, acc = 0.f;
#pragma unroll
    for (int c = 0; c < 4; c++) {
      float w = __expf(part_m[(bk * 4 + c) * 64 + qrow] - M);
      lsum += part_l[(bk * 4 + c) * 64 + qrow] * w;
      acc  += part_ctx[((size_t)(bk * 4 + c) * 64 + qrow) * HD_ + hd] * w;
    }
    float val = acc / lsum;
    int r = qrow >> 4, s = qrow & 15;
    ctx[(size_t)(b * 16 + s) * D_ + (kvh * 4 + r) * HD_ + hd] = val;
  }
}

extern "C" void kernel_launch(void* const* d_in, const int* in_sizes, int n_in,
                              void* d_out, int out_size, void* d_ws, size_t ws_size,
                              hipStream_t stream)
{
  const float* x       = (const float*)d_in[0];
  const float* Wq      = (const float*)d_in[1];
  const float* Wk      = (const float*)d_in[2];
  const float* Wv      = (const float*)d_in[3];
  const float* Wo      = (const float*)d_in[4];
  const float* cache_k = (const float*)d_in[5];
  const float* cache_v = (const float*)d_in[6];
  const int*   sp      = (const int*)d_in[7];

  char* w = (char*)d_ws;
  auto alloc = [&](size_t bytes) { char* p = w; w += (bytes + 255) & ~(size_t)255; return p; };
  short* Wq_t = (short*)alloc((size_t)4096 * 4096 * 2);
  short* Wk_t = (short*)alloc((size_t)1024 * 4096 * 2);
  short* Wv_t = (short*)alloc((size_t)1024 * 4096 * 2);
  short* Wo_t = (short*)alloc((size_t)4096 * 4096 * 2);
  short* q_bf = (short*)alloc((size_t)M_ * 4096 * 2);
  short* k_bf = (short*)alloc((size_t)M_ * 1024 * 2);
  short* v_bf = (short*)alloc((size_t)M_ * 1024 * 2);
  float* part_ctx = (float*)alloc((size_t)512 * 64 * 128 * 4);
  float* part_m   = (float*)alloc((size_t)512 * 64 * 4);
  float* part_l   = (float*)alloc((size_t)512 * 64 * 4);
  float* ctx      = (float*)alloc((size_t)M_ * 4096 * 4);

  dim3 tb(32, 8);
  transpose_convert<<<dim3(4096 / 32, 4096 / 32), tb, 0, stream>>>(Wq, Wq_t, 4096, 4096);
  transpose_convert<<<dim3(1024 / 32, 4096 / 32), tb, 0, stream>>>(Wk, Wk_t, 4096, 1024);
  transpose_convert<<<dim3(1024 / 32, 4096 / 32), tb, 0, stream>>>(Wv, Wv_t, 4096, 1024);
  transpose_convert<<<dim3(4096 / 32, 4096 / 32), tb, 0, stream>>>(Wo, Wo_t, 4096, 4096);

  gemm_bt<1><<<dim3(4096 / 64, M_ / 64), 256, 0, stream>>>(x, Wq_t, (void*)q_bf, 4096, 4096, sp);
  gemm_bt<1><<<dim3(1024 / 64, M_ / 64), 256, 0, stream>>>(x, Wk_t, (void*)k_bf, 1024, 4096, sp);
  gemm_bt<0><<<dim3(1024 / 64, M_ / 64), 256, 0, stream>>>(x, Wv_t, (void*)v_bf, 1024, 4096, sp);

  attn_kernel<<<dim3(4, 8, 16), 256, 0, stream>>>(q_bf, k_bf, v_bf, cache_k, cache_v,
                                                  part_ctx, part_m, part_l, sp);
  combine_kernel<<<128, 256, 0, stream>>>(part_ctx, part_m, part_l, ctx);

  gemm_bt<2><<<dim3(4096 / 64, M_ / 64), 256, 0, stream>>>(ctx, Wo_t, d_out, 4096, 4096, sp);
}

// Round 2
// 891.763 us; speedup vs baseline: 1.4165x; 1.4165x over previous
//
#include <hip/hip_runtime.h>
#include <hip/hip_bf16.h>

#define D_    4096
#define KVH_  8
#define HD_   128
#define MAXS_ 4096
#define M_    256
#define NCH   8                  // kv split chunks
#define TPC   (MAXS_ / NCH)      // 512 kv positions per chunk

using frag_ab = __attribute__((ext_vector_type(8))) short;   // 8 x bf16
using frag_cd = __attribute__((ext_vector_type(4))) float;   // 4 x f32

__device__ __forceinline__ short bfb(float f) {
  union { float f; unsigned u; } cv; cv.f = f;
  unsigned u = cv.u;
  return (short)((u + 0x7fffu + ((u >> 16) & 1u)) >> 16);  // RN-even fp32->bf16
}

// ---------------- prep: all 4 weight transposes (f32 KxN -> bf16 NxK) + x -> bf16 ----
// tiles: Wq 0..4095, Wk 4096..5119, Wv 5120..6143, Wo 6144..10239, x-convert 10240..10255
__global__ __launch_bounds__(256) void prep_kernel(
    const float* __restrict__ Wq, const float* __restrict__ Wk,
    const float* __restrict__ Wv, const float* __restrict__ Wo,
    const float* __restrict__ x,
    short* __restrict__ Wqkv_t,   // [6144][4096]: rows 0..4095 q, 4096..5119 k, 5120..6143 v
    short* __restrict__ Wo_t,     // [4096][4096]
    short* __restrict__ x_bf)     // [256][4096]
{
  int idx = blockIdx.x;
  int tid = threadIdx.x;
  if (idx >= 10240) {
    int j0 = (idx - 10240) * 256 + tid;
    const float4* xs = (const float4*)x;
    for (int j = j0; j < (M_ * D_) / 4; j += 16 * 256) {
      float4 v = xs[j];
      short4 o; o.x = bfb(v.x); o.y = bfb(v.y); o.z = bfb(v.z); o.w = bfb(v.w);
      *(short4*)(x_bf + (size_t)j * 4) = o;
    }
    return;
  }
  const float* W; short* Wt; int N; int tile;
  if (idx < 4096)      { W = Wq; Wt = Wqkv_t;                          N = 4096; tile = idx; }
  else if (idx < 5120) { W = Wk; Wt = Wqkv_t + (size_t)4096 * 4096;    N = 1024; tile = idx - 4096; }
  else if (idx < 6144) { W = Wv; Wt = Wqkv_t + (size_t)5120 * 4096;    N = 1024; tile = idx - 5120; }
  else                 { W = Wo; Wt = Wo_t;                            N = 4096; tile = idx - 6144; }
  int ntn = N >> 6;
  int tk = tile / ntn, tn = tile - tk * ntn;
  int k0 = tk << 6, n0 = tn << 6;
  __shared__ short tb[64 * 66];   // [col][row], stride 66 -> 2-way conflicts (free)
#pragma unroll
  for (int p = 0; p < 4; p++) {
    int seg = p * 256 + tid;
    int r = seg >> 4, c4 = (seg & 15) << 2;
    float4 v = *(const float4*)(W + (size_t)(k0 + r) * N + n0 + c4);
    tb[(c4 + 0) * 66 + r] = bfb(v.x);
    tb[(c4 + 1) * 66 + r] = bfb(v.y);
    tb[(c4 + 2) * 66 + r] = bfb(v.z);
    tb[(c4 + 3) * 66 + r] = bfb(v.w);
  }
  __syncthreads();
#pragma unroll
  for (int p = 0; p < 4; p++) {
    int seg = p * 256 + tid;
    int n = seg >> 4, c4 = (seg & 15) << 2;
    short4 o;
    o.x = tb[n * 66 + c4 + 0];
    o.y = tb[n * 66 + c4 + 1];
    o.z = tb[n * 66 + c4 + 2];
    o.w = tb[n * 66 + c4 + 3];
    *(short4*)(Wt + (size_t)(n0 + n) * 4096 + k0 + c4) = o;
  }
}

// ---------------- GEMM: A bf16 [M][4096] x Bt bf16 [N][4096] ----------------
// MODE 0: fused QKV epilogue (RoPE on n<5120, route to q/k/v bf16)
// MODE 1: f32 out
#define LDT 72

template<int MODE>
__global__ __launch_bounds__(256) void gemm_bf(
    const short* __restrict__ A, const short* __restrict__ Bt,
    short* __restrict__ q_bf, short* __restrict__ k_bf, short* __restrict__ v_bf,
    float* __restrict__ Cf, const int* __restrict__ sp)
{
  __shared__ __align__(16) short lds_a[64 * LDT];
  __shared__ __align__(16) short lds_b[64 * LDT];
  int tid = threadIdx.x;
  int wave = tid >> 6, lane = tid & 63, quad = lane >> 4, l16 = lane & 15;
  int m0 = blockIdx.y * 64;
  int n0 = blockIdx.x * 64;

  const frag_cd fz = {0.f, 0.f, 0.f, 0.f};
  frag_cd acc[4];
#pragma unroll
  for (int i = 0; i < 4; i++) acc[i] = fz;

  for (int kk = 0; kk < 4096; kk += 64) {
    __syncthreads();
#pragma unroll
    for (int p = 0; p < 2; p++) {
      int seg = p * 256 + tid;
      int m = seg >> 3, k8 = (seg & 7) << 3;
      *(frag_ab*)(&lds_a[m * LDT + k8]) = *(const frag_ab*)(A + (size_t)(m0 + m) * 4096 + kk + k8);
      *(frag_ab*)(&lds_b[m * LDT + k8]) = *(const frag_ab*)(Bt + (size_t)(n0 + m) * 4096 + kk + k8);
    }
    __syncthreads();
#pragma unroll
    for (int k0 = 0; k0 < 64; k0 += 32) {
      frag_ab af = *(const frag_ab*)(&lds_a[(wave * 16 + l16) * LDT + k0 + quad * 8]);
#pragma unroll
      for (int nt = 0; nt < 4; nt++) {
        frag_ab bf = *(const frag_ab*)(&lds_b[(nt * 16 + l16) * LDT + k0 + quad * 8]);
        acc[nt] = __builtin_amdgcn_mfma_f32_16x16x32_bf16(af, bf, acc[nt], 0, 0, 0);
      }
    }
  }

  int start_pos = (MODE == 0) ? *sp : 0;
#pragma unroll
  for (int nt = 0; nt < 4; nt++) {
    int n = n0 + nt * 16 + l16;
#pragma unroll
    for (int r = 0; r < 4; r++) {
      int m = m0 + wave * 16 + quad * 4 + r;
      float v = acc[nt][r];
      if (MODE == 1) {
        Cf[(size_t)m * 4096 + n] = v;
      } else {
        float outv = v;
        if (n < 5120) {   // RoPE for q and k columns
          float partner = __shfl_xor(v, 1);
          int hd = n & (HD_ - 1);
          float theta = exp2f(-(float)(hd >> 1) * 0.2076205059304601f);  // log2(10000)/64
          float fr = (float)(start_pos + (m & 15)) * theta;
          float sn, cs;
          sincosf(fr, &sn, &cs);
          outv = v * cs + ((n & 1) ? partner * sn : -partner * sn);
        }
        short ob = bfb(outv);
        if (n < 4096)      q_bf[(size_t)m * 4096 + n] = ob;
        else if (n < 5120) k_bf[(size_t)m * 1024 + n - 4096] = ob;
        else               v_bf[(size_t)m * 1024 + n - 5120] = ob;
      }
    }
  }
}

// ---------------- flash attention, split-kv (8 chunks) ----------------
#define KLD 136   // k_s stride (2-way-free reads)
#define VLD 72    // vT stride, t-block XOR swizzled (2-way stores AND reads)
#define PLD 72

__global__ __launch_bounds__(256, 4) void attn_kernel(
    const short* __restrict__ qb,        // 256 x 4096 bf16 (rope'd)
    const short* __restrict__ kb,        // 256 x 1024 bf16 (rope'd new keys)
    const short* __restrict__ vb,        // 256 x 1024 bf16
    const float* __restrict__ cache_k,   // 16 x 4096 x 8 x 128 f32
    const float* __restrict__ cache_v,
    float* __restrict__ part_ctx,        // [1024][64][128]
    float* __restrict__ part_m,          // [1024][64]
    float* __restrict__ part_l,
    const int* __restrict__ sp)
{
  __shared__ __align__(16) short k_s[64 * KLD];   // 17408 B
  __shared__ __align__(16) short vT[HD_ * VLD];   // 18432 B
  short* p_s = k_s;                               // aliased (extra barrier guards it)

  int chunk = blockIdx.x, kvh = blockIdx.y, b = blockIdx.z;
  int tid = threadIdx.x;
  int wave = tid >> 6, lane = tid & 63, quad = lane >> 4, l16 = lane & 15;
  int start_pos = *sp;

  frag_ab qf[4];
  {
    const short* qrow = qb + (size_t)(b * 16 + l16) * D_ + (kvh * 4 + wave) * HD_;
#pragma unroll
    for (int k0 = 0; k0 < 4; k0++)
      qf[k0] = *(const frag_ab*)(qrow + k0 * 32 + quad * 8);
  }

  const frag_cd fz = {0.f, 0.f, 0.f, 0.f};
  frag_cd acc_o[8];
#pragma unroll
  for (int i = 0; i < 8; i++) acc_o[i] = fz;
  float m_i[4], l_i[4];
#pragma unroll
  for (int r = 0; r < 4; r++) { m_i[r] = -1e30f; l_i[r] = 0.f; }

  int rloc = tid >> 5;
  int lane32 = tid & 31;
  int hd4 = lane32 * 4;
  const float scale = 0.08838834764831845f;

  for (int it = 0; it < TPC / 64; it++) {
    int t0 = chunk * TPC + it * 64;
    __syncthreads();   // A: prior PV reads done
#pragma unroll
    for (int pass = 0; pass < 8; pass++) {
      int row = pass * 8 + rloc;
      int t = t0 + row;
      short4 kq, vq;
      if (t < start_pos) {
        size_t off = (((size_t)b * MAXS_ + t) * KVH_ + kvh) * HD_ + hd4;
        float4 k4 = *(const float4*)(cache_k + off);
        float4 v4 = *(const float4*)(cache_v + off);
        kq.x = bfb(k4.x); kq.y = bfb(k4.y); kq.z = bfb(k4.z); kq.w = bfb(k4.w);
        vq.x = bfb(v4.x); vq.y = bfb(v4.y); vq.z = bfb(v4.z); vq.w = bfb(v4.w);
      } else {
        int s = t - start_pos;
        size_t off = (size_t)(b * 16 + s) * (KVH_ * HD_) + kvh * HD_ + hd4;
        kq = *(const short4*)(kb + off);
        vq = *(const short4*)(vb + off);
      }
      *(short4*)(&k_s[row * KLD + hd4]) = kq;
      int cb = row >> 3, wi = row & 7;
      {
        int hd = hd4 + 0; vT[hd * VLD + (((cb ^ ((hd >> 3) & 7)) << 3) | wi)] = kq.x = vq.x, vq.x;
      }
      // (explicit, no comma tricks:)
      vT[(hd4 + 0) * VLD + (((cb ^ (((hd4 + 0) >> 3) & 7)) << 3) | wi)] = vq.x;
      vT[(hd4 + 1) * VLD + (((cb ^ (((hd4 + 1) >> 3) & 7)) << 3) | wi)] = vq.y;
      vT[(hd4 + 2) * VLD + (((cb ^ (((hd4 + 2) >> 3) & 7)) << 3) | wi)] = vq.z;
      vT[(hd4 + 3) * VLD + (((cb ^ (((hd4 + 3) >> 3) & 7)) << 3) | wi)] = vq.w;
    }
    __syncthreads();   // B: tiles staged

    frag_cd sc[4];
#pragma unroll
    for (int i = 0; i < 4; i++) sc[i] = fz;
#pragma unroll
    for (int k0 = 0; k0 < HD_; k0 += 32) {
#pragma unroll
      for (int nt = 0; nt < 4; nt++) {
        frag_ab bfm = *(const frag_ab*)(&k_s[(nt * 16 + l16) * KLD + k0 + quad * 8]);
        sc[nt] = __builtin_amdgcn_mfma_f32_16x16x32_bf16(qf[k0 >> 5], bfm, sc[nt], 0, 0, 0);
      }
    }

    float alpha[4];
#pragma unroll
    for (int r = 0; r < 4; r++) {
      float mx = fmaxf(fmaxf(sc[0][r], sc[1][r]), fmaxf(sc[2][r], sc[3][r])) * scale;
#pragma unroll
      for (int off = 1; off < 16; off <<= 1) mx = fmaxf(mx, __shfl_xor(mx, off));
      float mnew = fmaxf(m_i[r], mx);
      alpha[r] = __expf(m_i[r] - mnew);
      m_i[r] = mnew;
      float rsum = 0.f;
#pragma unroll
      for (int nt = 0; nt < 4; nt++) {
        float p = __expf(sc[nt][r] * scale - mnew);
        sc[nt][r] = p;
        rsum += p;
      }
#pragma unroll
      for (int off = 1; off < 16; off <<= 1) rsum += __shfl_xor(rsum, off);
      l_i[r] = l_i[r] * alpha[r] + rsum;
    }
#pragma unroll
    for (int nt = 0; nt < 8; nt++)
#pragma unroll
      for (int r = 0; r < 4; r++) acc_o[nt][r] *= alpha[r];

    __syncthreads();   // C: all QK reads of k_s done before p_s overwrites it
#pragma unroll
    for (int r = 0; r < 4; r++)
#pragma unroll
      for (int nt = 0; nt < 4; nt++)
        p_s[(wave * 16 + quad * 4 + r) * PLD + nt * 16 + l16] = bfb(sc[nt][r]);

#pragma unroll
    for (int k0 = 0; k0 < 64; k0 += 32) {
      frag_ab af = *(const frag_ab*)(&p_s[(wave * 16 + l16) * PLD + k0 + quad * 8]);
      int tb = (k0 >> 3) + quad;
#pragma unroll
      for (int nt = 0; nt < 8; nt++) {
        int hd = nt * 16 + l16;
        frag_ab bfm = *(const frag_ab*)(&vT[hd * VLD + ((tb ^ ((hd >> 3) & 7)) << 3)]);
        acc_o[nt] = __builtin_amdgcn_mfma_f32_16x16x32_bf16(af, bfm, acc_o[nt], 0, 0, 0);
      }
    }
  }

  int blk = ((b * 8 + kvh) << 3) + chunk;
#pragma unroll
  for (int nt = 0; nt < 8; nt++)
#pragma unroll
    for (int r = 0; r < 4; r++) {
      int qrow = wave * 16 + quad * 4 + r;
      part_ctx[((size_t)blk * 64 + qrow) * HD_ + nt * 16 + l16] = acc_o[nt][r];
    }
  if (l16 == 0) {
#pragma unroll
    for (int r = 0; r < 4; r++) {
      int qrow = wave * 16 + quad * 4 + r;
      part_m[blk * 64 + qrow] = m_i[r];
      part_l[blk * 64 + qrow] = l_i[r];
    }
  }
}

// ---------------- combine split-kv partials -> ctx bf16 ----------------
__global__ __launch_bounds__(256) void combine_kernel(
    const float* __restrict__ part_ctx, const float* __restrict__ part_m,
    const float* __restrict__ part_l, short* __restrict__ ctx_bf)
{
  int bk = blockIdx.x;            // b*8 + kvh
  int b = bk >> 3, kvh = bk & 7;
  int tid = threadIdx.x;
  __shared__ float w_s[8][64];
  __shared__ float inv_l[64];
  if (tid < 64) {
    float M = -1e30f;
#pragma unroll
    for (int c = 0; c < 8; c++) M = fmaxf(M, part_m[(bk * 8 + c) * 64 + tid]);
    float ls = 0.f;
#pragma unroll
    for (int c = 0; c < 8; c++) {
      float w = __expf(part_m[(bk * 8 + c) * 64 + tid] - M);
      w_s[c][tid] = w;
      ls += part_l[(bk * 8 + c) * 64 + tid] * w;
    }
    inv_l[tid] = 1.f / ls;
  }
  __syncthreads();
  for (int idx = tid; idx < 64 * 128; idx += 256) {
    int qrow = idx >> 7, hd = idx & 127;
    float acc = 0.f;
#pragma unroll
    for (int c = 0; c < 8; c++)
      acc += part_ctx[((size_t)(bk * 8 + c) * 64 + qrow) * HD_ + hd] * w_s[c][qrow];
    float val = acc * inv_l[qrow];
    int r = qrow >> 4, s = qrow & 15;
    ctx_bf[(size_t)(b * 16 + s) * D_ + (kvh * 4 + r) * HD_ + hd] = bfb(val);
  }
}

extern "C" void kernel_launch(void* const* d_in, const int* in_sizes, int n_in,
                              void* d_out, int out_size, void* d_ws, size_t ws_size,
                              hipStream_t stream)
{
  const float* x       = (const float*)d_in[0];
  const float* Wq      = (const float*)d_in[1];
  const float* Wk      = (const float*)d_in[2];
  const float* Wv      = (const float*)d_in[3];
  const float* Wo      = (const float*)d_in[4];
  const float* cache_k = (const float*)d_in[5];
  const float* cache_v = (const float*)d_in[6];
  const int*   sp      = (const int*)d_in[7];

  char* w = (char*)d_ws;
  auto alloc = [&](size_t bytes) { char* p = w; w += (bytes + 255) & ~(size_t)255; return p; };
  short* Wqkv_t = (short*)alloc((size_t)6144 * 4096 * 2);
  short* Wo_t   = (short*)alloc((size_t)4096 * 4096 * 2);
  short* x_bf   = (short*)alloc((size_t)M_ * 4096 * 2);
  short* q_bf   = (short*)alloc((size_t)M_ * 4096 * 2);
  short* k_bf   = (short*)alloc((size_t)M_ * 1024 * 2);
  short* v_bf   = (short*)alloc((size_t)M_ * 1024 * 2);
  short* ctx_bf = (short*)alloc((size_t)M_ * 4096 * 2);
  float* part_ctx = (float*)alloc((size_t)1024 * 64 * 128 * 4);
  float* part_m   = (float*)alloc((size_t)1024 * 64 * 4);
  float* part_l   = (float*)alloc((size_t)1024 * 64 * 4);

  prep_kernel<<<10256, 256, 0, stream>>>(Wq, Wk, Wv, Wo, x, Wqkv_t, Wo_t, x_bf);

  gemm_bf<0><<<dim3(6144 / 64, M_ / 64), 256, 0, stream>>>(
      x_bf, Wqkv_t, q_bf, k_bf, v_bf, nullptr, sp);

  attn_kernel<<<dim3(NCH, 8, 16), 256, 0, stream>>>(
      q_bf, k_bf, v_bf, cache_k, cache_v, part_ctx, part_m, part_l, sp);

  combine_kernel<<<128, 256, 0, stream>>>(part_ctx, part_m, part_l, ctx_bf);

  gemm_bf<1><<<dim3(4096 / 64, M_ / 64), 256, 0, stream>>>(
      ctx_bf, Wo_t, nullptr, nullptr, nullptr, (float*)d_out, sp);
}